// Round 5
// baseline (323.397 us; speedup 1.0000x reference)
//
#include <hip/hip_runtime.h>
#include <hip/hip_bf16.h>

#define NN 10000
#define KK 32
#define DDIRIN 10
#define DDIR 64
#define DD 128          // D_DIST == D_DIST_IN == D_ATOM == 128

typedef short bf16x8 __attribute__((ext_vector_type(8)));
typedef float f32x4  __attribute__((ext_vector_type(4)));
typedef float f32x2  __attribute__((ext_vector_type(2)));

__device__ __forceinline__ float silu_f(float x) { return x / (1.0f + __expf(-x)); }

// packed f32x2 -> bf16x2 (RNE) -> raw shorts
__device__ __forceinline__ ushort2 pk_bf16(float a, float b) {
    __hip_bfloat162 h = __float22bfloat162_rn(float2{a, b});
    union { __hip_bfloat162 h; ushort2 u; } v; v.h = h;
    return v.u;
}

// ---- Kernel 1: dir MLPs (10->64 x2) into ws, PLUS dWb bf16 pack (32 blocks) ----
__global__ __launch_bounds__(256) void dirprep_kernel(
    const float* __restrict__ nde,
    const float* __restrict__ sW, const float* __restrict__ sb,
    const float* __restrict__ tW, const float* __restrict__ tb,
    const float* __restrict__ dW,
    float* __restrict__ sd, float* __restrict__ td, ushort* __restrict__ dWb)
{
    int b = blockIdx.x;
    if (b < 32) {
        // dWb[ncol][k] = bf16(dW[k][ncol])  (col-major bf16, 32 KB)
        int v = b * 256 + threadIdx.x;        // 0..8191
        int ncol = v >> 6;
        int k0   = (v & 63) * 2;
        ushort2 u = pk_bf16(dW[k0 * DD + ncol], dW[(k0 + 1) * DD + ncol]);
        *reinterpret_cast<ushort2*>(&dWb[ncol * DD + k0]) = u;
        return;
    }
    int gid = (b - 32) * 256 + threadIdx.x;   // 0..639999 exactly
    int n = gid >> 6, d = gid & 63;
    float a = sb[d], t = tb[d];
    const float* x = nde + n * DDIRIN;
#pragma unroll
    for (int i = 0; i < DDIRIN; ++i) {
        float xv = x[i];
        a = fmaf(xv, sW[i * DDIR + d], a);
        t = fmaf(xv, tW[i * DDIR + d], t);
    }
    sd[gid] = silu_f(a);
    td[gid] = silu_f(t);
}

// ---- Kernel 2: cols 0..128. Barrier-free, LDS-free MFMA GEMM. ----
// 2 nodes (64 edge rows) per block, 4 waves; wave owns 32 cols, all 4 row-tiles.
// A fragments loaded straight from global (2x16B per (rt,t)), cvt f32->bf16 in
// regs; the 4 waves read identical A rows -> L1 broadcast. Masked rows are NOT
// zeroed; epilogue selects per element via the row ballot.
template<bool PREB>
__global__ __launch_bounds__(256, 4) void gemm_kernel(
    const float* __restrict__ edist,   // [N,32,128]
    const int*   __restrict__ nmask,   // [N,32]
    const float* __restrict__ dW,      // [128,128]
    const float* __restrict__ db,      // [128]
    const ushort* __restrict__ dWb,    // [128,128] bf16 col-major (or null)
    float* __restrict__ out)           // [N,512]
{
    const int tid  = threadIdx.x;
    const int wid  = tid >> 6;
    const int lane = tid & 63;
    const int l15  = lane & 15;
    const int quad = lane >> 4;
    const int n0   = blockIdx.x * 2;

    // row-activity ballot: lane l <-> edge row l of this 2-node tile
    bool act = (nmask[n0 * KK + lane] != 0);
    unsigned long long bits = __ballot(act);
    const float cnt0 = (float)__popcll(bits & 0xffffffffull);
    const float cnt1 = (float)__popcll(bits >> 32);

    // B fragments: lane holds k = t*32 + quad*8 .. +8, col = (2*wid+c2)*16+l15
    bf16x8 bfrag[2][4];
    float  bias[2];
    if constexpr (PREB) {
#pragma unroll
        for (int c2 = 0; c2 < 2; ++c2) {
            int ncol = (2 * wid + c2) * 16 + l15;
            bias[c2] = db[ncol];
#pragma unroll
            for (int t = 0; t < 4; ++t)
                bfrag[c2][t] = *reinterpret_cast<const bf16x8*>(
                    &dWb[ncol * DD + t * 32 + quad * 8]);
        }
    } else {
#pragma unroll
        for (int c2 = 0; c2 < 2; ++c2) {
            int ncol = (2 * wid + c2) * 16 + l15;
            bias[c2] = db[ncol];
#pragma unroll
            for (int t = 0; t < 4; ++t) {
                bf16x8 v;
#pragma unroll
                for (int j2 = 0; j2 < 4; ++j2) {
                    int k0 = t * 32 + quad * 8 + 2 * j2;
                    ushort2 u = pk_bf16(dW[k0 * DD + ncol], dW[(k0 + 1) * DD + ncol]);
                    v[2 * j2]     = (short)u.x;
                    v[2 * j2 + 1] = (short)u.y;
                }
                bfrag[c2][t] = v;
            }
        }
    }

    // MFMA over 4 row-tiles; A direct from global (no LDS, no barrier).
    f32x4 acc[4][2];
#pragma unroll
    for (int rt = 0; rt < 4; ++rt)
#pragma unroll
        for (int c2 = 0; c2 < 2; ++c2)
#pragma unroll
            for (int g = 0; g < 4; ++g) acc[rt][c2][g] = 0.0f;

    const float* Ebase = edist + (size_t)n0 * (KK * DD);
#pragma unroll
    for (int rt = 0; rt < 4; ++rt) {
        const float* rp = Ebase + (size_t)(rt * 16 + l15) * DD + quad * 8;
        bf16x8 af[4];
#pragma unroll
        for (int t = 0; t < 4; ++t) {
            f32x4 a = *reinterpret_cast<const f32x4*>(rp + t * 32);
            f32x4 b = *reinterpret_cast<const f32x4*>(rp + t * 32 + 4);
            ushort2 u0 = pk_bf16(a[0], a[1]), u1 = pk_bf16(a[2], a[3]);
            ushort2 u2 = pk_bf16(b[0], b[1]), u3 = pk_bf16(b[2], b[3]);
            bf16x8 v;
            v[0] = (short)u0.x; v[1] = (short)u0.y; v[2] = (short)u1.x; v[3] = (short)u1.y;
            v[4] = (short)u2.x; v[5] = (short)u2.y; v[6] = (short)u3.x; v[7] = (short)u3.y;
            af[t] = v;
        }
#pragma unroll
        for (int t = 0; t < 4; ++t) {
            acc[rt][0] = __builtin_amdgcn_mfma_f32_16x16x32_bf16(af[t], bfrag[0][t], acc[rt][0], 0, 0, 0);
            acc[rt][1] = __builtin_amdgcn_mfma_f32_16x16x32_bf16(af[t], bfrag[1][t], acc[rt][1], 0, 0, 0);
        }
    }

    // Epilogue. D layout: col=l15, row=quad*4+g (+16*rt). Mask per element via ballot.
#pragma unroll
    for (int c2 = 0; c2 < 2; ++c2) {
#pragma unroll
        for (int nd = 0; nd < 2; ++nd) {
            float p = 0.0f;
#pragma unroll
            for (int h = 0; h < 2; ++h) {
                int rt = 2 * nd + h;
                int rbase = rt * 16 + quad * 4;
#pragma unroll
                for (int g = 0; g < 4; ++g) {
                    bool on = (bits >> (rbase + g)) & 1ull;
                    float s = silu_f(acc[rt][c2][g] + bias[c2]);
                    p += on ? s : 0.0f;
                }
            }
            p += __shfl_xor(p, 16);
            p += __shfl_xor(p, 32);
            if (quad == nd) {
                float c = (nd == 0) ? cnt0 : cnt1;
                __builtin_nontemporal_store(p / (c + 1e-5f),
                    &out[(size_t)(n0 + nd) * 512 + (2 * wid + c2) * 16 + l15]);
            }
        }
    }
}

// ---- Kernel 3: dims 128..512. One wave per node; ballot-compacted neighbor list. ----
template<bool USE_WS>
__global__ __launch_bounds__(256) void seg_kernel(
    const int*   __restrict__ an,      // [N]
    const float* __restrict__ nde,     // [N,10]
    const int*   __restrict__ nl,      // [N,32]
    const int*   __restrict__ nmask,   // [N,32]
    const float* __restrict__ semb,    // [100,128]
    const float* __restrict__ temb,    // [100,128]
    const float* __restrict__ sW, const float* __restrict__ sb,
    const float* __restrict__ tW, const float* __restrict__ tb,
    const float* __restrict__ sd_ws,   // [N,64] or null
    const float* __restrict__ td_ws,   // [N,64] or null
    float* __restrict__ out)           // [N,512]
{
    const int tid  = threadIdx.x;
    const int wid  = tid >> 6;
    const int lane = tid & 63;
    const int n    = blockIdx.x * 4 + wid;

    __shared__ int s_idx[4][KK];
    __shared__ int s_aidx[4][KK];

    int j = 0; bool act = false;
    if (lane < KK) {
        j   = nl[n * KK + lane];
        act = (nmask[n * KK + lane] != 0);
    }
    unsigned long long bits = __ballot(act);
    int cnt = (int)__popcll(bits);
    if (act) {
        int rank = (int)__popcll(bits & ((1ull << lane) - 1ull));
        s_idx[wid][rank]  = j;
        s_aidx[wid][rank] = an[j];
    }
    __syncthreads();

    const float invv  = 1.0f / ((float)cnt + 1e-5f);
    const float scale = (float)cnt * invv;
    float* outn = out + (size_t)n * 512;

    // sender dir (128..192), d = lane
    {
        float s = 0.0f;
        if constexpr (USE_WS) {
#pragma unroll 4
            for (int i = 0; i < cnt; ++i)
                s += sd_ws[s_idx[wid][i] * DDIR + lane];
        } else {
            for (int i = 0; i < cnt; ++i) {
                int jj = s_idx[wid][i];
                float a = sb[lane];
#pragma unroll
                for (int q = 0; q < DDIRIN; ++q)
                    a = fmaf(nde[jj * DDIRIN + q], sW[q * DDIR + lane], a);
                s += silu_f(a);
            }
        }
        outn[128 + lane] = s * invv;
    }

    // sender atom (192..320)
    {
        float s0 = 0.0f, s1 = 0.0f;
#pragma unroll 4
        for (int i = 0; i < cnt; ++i) {
            int a = s_aidx[wid][i];
            s0 += semb[a * DD + lane];
            s1 += semb[a * DD + 64 + lane];
        }
        outn[192 + lane] = s0 * invv;
        outn[256 + lane] = s1 * invv;
    }

    // recv dir (320..384)
    {
        float tdv;
        if constexpr (USE_WS) {
            tdv = td_ws[n * DDIR + lane];
        } else {
            float a = tb[lane];
#pragma unroll
            for (int q = 0; q < DDIRIN; ++q)
                a = fmaf(nde[n * DDIRIN + q], tW[q * DDIR + lane], a);
            tdv = silu_f(a);
        }
        outn[320 + lane] = tdv * scale;
    }

    // recv atom (384..512)
    {
        int ann = an[n];
        outn[384 + lane] = temb[ann * DD + lane] * scale;
        outn[448 + lane] = temb[ann * DD + 64 + lane] * scale;
    }
}

extern "C" void kernel_launch(void* const* d_in, const int* in_sizes, int n_in,
                              void* d_out, int out_size, void* d_ws, size_t ws_size,
                              hipStream_t stream) {
    const int*   an    = (const int*)  d_in[0];
    const float* nde   = (const float*)d_in[1];
    const float* edist = (const float*)d_in[2];
    const int*   nl    = (const int*)  d_in[3];
    const int*   nmask = (const int*)  d_in[4];
    const float* semb  = (const float*)d_in[5];
    const float* temb  = (const float*)d_in[6];
    const float* sW    = (const float*)d_in[7];
    const float* sb    = (const float*)d_in[8];
    const float* tW    = (const float*)d_in[9];
    const float* tb    = (const float*)d_in[10];
    const float* dW    = (const float*)d_in[11];
    const float* db    = (const float*)d_in[12];
    float* out = (float*)d_out;

    const size_t dwb_bytes = (size_t)DD * DD * sizeof(ushort);              // 32 KB
    const size_t need = dwb_bytes + (size_t)NN * DDIR * sizeof(float) * 2;  // +5.12 MB

    if (ws_size >= need) {
        ushort* dWb = (ushort*)d_ws;
        float*  sd  = (float*)((char*)d_ws + dwb_bytes);
        float*  td  = sd + (size_t)NN * DDIR;
        dirprep_kernel<<<32 + NN * DDIR / 256, 256, 0, stream>>>(
            nde, sW, sb, tW, tb, dW, sd, td, dWb);
        gemm_kernel<true><<<NN / 2, 256, 0, stream>>>(edist, nmask, dW, db, dWb, out);
        seg_kernel<true><<<NN / 4, 256, 0, stream>>>(
            an, nde, nl, nmask, semb, temb, sW, sb, tW, tb, sd, td, out);
    } else {
        gemm_kernel<false><<<NN / 2, 256, 0, stream>>>(edist, nmask, dW, db, nullptr, out);
        seg_kernel<false><<<NN / 4, 256, 0, stream>>>(
            an, nde, nl, nmask, semb, temb, sW, sb, tW, tb, nullptr, nullptr, out);
    }
}

// Round 6
// 282.608 us; speedup vs baseline: 1.1443x; 1.1443x over previous
//
#include <hip/hip_runtime.h>
#include <hip/hip_bf16.h>

#define NN 10000
#define KK 32
#define DDIRIN 10
#define DDIR 64
#define DD 128          // D_DIST == D_DIST_IN == D_ATOM == 128

typedef short bf16x8 __attribute__((ext_vector_type(8)));
typedef float f32x4  __attribute__((ext_vector_type(4)));
typedef float f32x2  __attribute__((ext_vector_type(2)));

__device__ __forceinline__ float silu_f(float x) { return x / (1.0f + __expf(-x)); }

// packed f32x2 -> bf16x2 (RNE) -> raw shorts
__device__ __forceinline__ ushort2 pk_bf16(float a, float b) {
    __hip_bfloat162 h = __float22bfloat162_rn(float2{a, b});
    union { __hip_bfloat162 h; ushort2 u; } v; v.h = h;
    return v.u;
}

// ---- Kernel 1: dir MLPs (10->64 x2) into ws, PLUS dWb bf16 pack (32 blocks) ----
// Runs FIRST: gemm consumes dWb.
__global__ __launch_bounds__(256) void dirprep_kernel(
    const float* __restrict__ nde,
    const float* __restrict__ sW, const float* __restrict__ sb,
    const float* __restrict__ tW, const float* __restrict__ tb,
    const float* __restrict__ dW,
    float* __restrict__ sd, float* __restrict__ td, ushort* __restrict__ dWb)
{
    int b = blockIdx.x;
    if (b < 32) {
        // dWb[ncol][k] = bf16(dW[k][ncol])  (col-major bf16, 32 KB)
        int v = b * 256 + threadIdx.x;        // 0..8191
        int ncol = v >> 6;
        int k0   = (v & 63) * 2;
        ushort2 u = pk_bf16(dW[k0 * DD + ncol], dW[(k0 + 1) * DD + ncol]);
        *reinterpret_cast<ushort2*>(&dWb[ncol * DD + k0]) = u;
        return;
    }
    int gid = (b - 32) * 256 + threadIdx.x;   // 0..639999 exactly
    int n = gid >> 6, d = gid & 63;
    float a = sb[d], t = tb[d];
    const float* x = nde + n * DDIRIN;
#pragma unroll
    for (int i = 0; i < DDIRIN; ++i) {
        float xv = x[i];
        a = fmaf(xv, sW[i * DDIR + d], a);
        t = fmaf(xv, tW[i * DDIR + d], t);
    }
    sd[gid] = silu_f(a);
    td[gid] = silu_f(t);
}

// ---- Kernel 2: dims 0..128. R0 structure: 4 nodes (=128 edge rows) per block. ----
// s_E: 128 rows x 16 kb-blocks of 8 bf16; block kb stored at kb ^ (row&7).
// Masked-off rows zeroed at staging; epilogue corrects with
//   sum_masked silu = sum_all silu - (32-cnt)*silu(bias).
// Changes vs R0: (a) two-phase staging — ALL 16 edist loads issued into
// registers before any cvt/ds_write (guaranteed 16KB/wave in flight);
// (b) bfrag loaded from pre-packed bf16 dWb (8x16B loads, no scalar prologue).
template<bool PREB>
__global__ __launch_bounds__(256, 2) void gemm_kernel(
    const float* __restrict__ edist,   // [N,32,128]
    const int*   __restrict__ nmask,   // [N,32]
    const float* __restrict__ dW,      // [128,128]
    const float* __restrict__ db,      // [128]
    const ushort* __restrict__ dWb,    // [128,128] bf16 col-major (or null)
    float* __restrict__ out)           // [N,512]
{
    const int tid  = threadIdx.x;
    const int wid  = tid >> 6;       // wave -> output cols [32*wid, 32*wid+32)
    const int lane = tid & 63;
    const int l15  = lane & 15;
    const int quad = lane >> 4;
    const int n0   = blockIdx.x * 4;

    __shared__ __align__(16) short s_E[128 * 128];   // 32 KB bf16, swizzled
    __shared__ float s_cnt[4];

    // ---- Phase A: issue ALL edist loads first (16 x 16B per thread) ----
    const f32x4* E4 = reinterpret_cast<const f32x4*>(edist + (size_t)n0 * (KK * DD));
    f32x4 va[8], vb[8];
#pragma unroll
    for (int i = 0; i < 8; ++i) {
        int f0 = 2 * tid + 512 * i;
        va[i] = E4[f0];
        vb[i] = E4[f0 + 1];
    }
    const int* nm = nmask + n0 * KK;
    int nmv[8];
#pragma unroll
    for (int i = 0; i < 8; ++i)
        nmv[i] = nm[(tid >> 4) + 16 * i];    // row of iter i

    // ---- B fragments (overlap staging latency) ----
    bf16x8 bfrag[2][4];
    float  bias[2];
    if constexpr (PREB) {
#pragma unroll
        for (int c2 = 0; c2 < 2; ++c2) {
            int ncol = (2 * wid + c2) * 16 + l15;
            bias[c2] = db[ncol];
#pragma unroll
            for (int t = 0; t < 4; ++t)
                bfrag[c2][t] = *reinterpret_cast<const bf16x8*>(
                    &dWb[ncol * DD + t * 32 + quad * 8]);
        }
    } else {
#pragma unroll
        for (int c2 = 0; c2 < 2; ++c2) {
            int ncol = (2 * wid + c2) * 16 + l15;
            bias[c2] = db[ncol];
#pragma unroll
            for (int t = 0; t < 4; ++t) {
                bf16x8 v;
#pragma unroll
                for (int j2 = 0; j2 < 4; ++j2) {
                    int k0 = t * 32 + quad * 8 + 2 * j2;
                    ushort2 u = pk_bf16(dW[k0 * DD + ncol], dW[(k0 + 1) * DD + ncol]);
                    v[2 * j2]     = (short)u.x;
                    v[2 * j2 + 1] = (short)u.y;
                }
                bfrag[c2][t] = v;
            }
        }
    }

    if (tid < 4) {
        int c = 0;
#pragma unroll 8
        for (int k = 0; k < KK; ++k) c += (nm[tid * KK + k] != 0) ? 1 : 0;
        s_cnt[tid] = (float)c;
    }

    // ---- Phase B: cvt f32->bf16, mask-zero, swizzled ds_write ----
#pragma unroll
    for (int i = 0; i < 8; ++i) {
        int f0  = 2 * tid + 512 * i;
        int row = f0 >> 5;
        f32x4 a = va[i], b = vb[i];
        ushort2 u0 = pk_bf16(a[0], a[1]), u1 = pk_bf16(a[2], a[3]);
        ushort2 u2 = pk_bf16(b[0], b[1]), u3 = pk_bf16(b[2], b[3]);
        bf16x8 v;
        v[0] = (short)u0.x; v[1] = (short)u0.y; v[2] = (short)u1.x; v[3] = (short)u1.y;
        v[4] = (short)u2.x; v[5] = (short)u2.y; v[6] = (short)u3.x; v[7] = (short)u3.y;
        bf16x8 z;
#pragma unroll
        for (int q = 0; q < 8; ++q) z[q] = 0;
        v = (nmv[i] != 0) ? v : z;
        int kb = tid & 15;
        int sw = kb ^ (row & 7);
        *reinterpret_cast<bf16x8*>(&s_E[row * 128 + sw * 8]) = v;
    }
    __syncthreads();   // the ONLY barrier

    // ---- MFMA: C[128 rows x 128 cols]; wave owns 32 cols, all 8 row-tiles. ----
    f32x4 acc[8][2];
#pragma unroll
    for (int rt = 0; rt < 8; ++rt)
#pragma unroll
        for (int c2 = 0; c2 < 2; ++c2)
#pragma unroll
            for (int g = 0; g < 4; ++g) acc[rt][c2][g] = 0.0f;

#pragma unroll
    for (int rt = 0; rt < 8; ++rt) {
        bf16x8 af[4];
        int r = rt * 16 + l15;
#pragma unroll
        for (int t = 0; t < 4; ++t) {
            int kb = (4 * t + quad) ^ (l15 & 7);
            af[t] = *reinterpret_cast<const bf16x8*>(&s_E[r * 128 + kb * 8]);
        }
#pragma unroll
        for (int t = 0; t < 4; ++t) {
            acc[rt][0] = __builtin_amdgcn_mfma_f32_16x16x32_bf16(af[t], bfrag[0][t], acc[rt][0], 0, 0, 0);
            acc[rt][1] = __builtin_amdgcn_mfma_f32_16x16x32_bf16(af[t], bfrag[1][t], acc[rt][1], 0, 0, 0);
        }
    }

    // ---- Epilogue. D layout: col=l15, row=quad*4+reg (+16*rt). Node nd = rows rt in {2nd,2nd+1}.
#pragma unroll
    for (int c2 = 0; c2 < 2; ++c2) {
        float sbv = silu_f(bias[c2]);
#pragma unroll
        for (int nd = 0; nd < 4; ++nd) {
            float p = 0.0f;
#pragma unroll
            for (int h = 0; h < 2; ++h) {
                int rt = 2 * nd + h;
#pragma unroll
                for (int g = 0; g < 4; ++g)
                    p += silu_f(acc[rt][c2][g] + bias[c2]);
            }
            p += __shfl_xor(p, 16);
            p += __shfl_xor(p, 32);
            if (quad == nd) {
                float c = s_cnt[nd];
                float val = (p - (32.0f - c) * sbv) / (c + 1e-5f);
                out[(size_t)(n0 + nd) * 512 + (2 * wid + c2) * 16 + l15] = val;
            }
        }
    }
}

// ---- Kernel 3: dims 128..512. One wave per node; ballot-compacted neighbor list. ----
template<bool USE_WS>
__global__ __launch_bounds__(256) void seg_kernel(
    const int*   __restrict__ an,      // [N]
    const float* __restrict__ nde,     // [N,10]
    const int*   __restrict__ nl,      // [N,32]
    const int*   __restrict__ nmask,   // [N,32]
    const float* __restrict__ semb,    // [100,128]
    const float* __restrict__ temb,    // [100,128]
    const float* __restrict__ sW, const float* __restrict__ sb,
    const float* __restrict__ tW, const float* __restrict__ tb,
    const float* __restrict__ sd_ws,   // [N,64] or null
    const float* __restrict__ td_ws,   // [N,64] or null
    float* __restrict__ out)           // [N,512]
{
    const int tid  = threadIdx.x;
    const int wid  = tid >> 6;
    const int lane = tid & 63;
    const int n    = blockIdx.x * 4 + wid;

    __shared__ int s_idx[4][KK];
    __shared__ int s_aidx[4][KK];

    int j = 0; bool act = false;
    if (lane < KK) {
        j   = nl[n * KK + lane];
        act = (nmask[n * KK + lane] != 0);
    }
    unsigned long long bits = __ballot(act);
    int cnt = (int)__popcll(bits);
    if (act) {
        int rank = (int)__popcll(bits & ((1ull << lane) - 1ull));
        s_idx[wid][rank]  = j;
        s_aidx[wid][rank] = an[j];
    }
    __syncthreads();

    const float invv  = 1.0f / ((float)cnt + 1e-5f);
    const float scale = (float)cnt * invv;
    float* outn = out + (size_t)n * 512;

    // sender dir (128..192), d = lane
    {
        float s = 0.0f;
        if constexpr (USE_WS) {
#pragma unroll 4
            for (int i = 0; i < cnt; ++i)
                s += sd_ws[s_idx[wid][i] * DDIR + lane];
        } else {
            for (int i = 0; i < cnt; ++i) {
                int jj = s_idx[wid][i];
                float a = sb[lane];
#pragma unroll
                for (int q = 0; q < DDIRIN; ++q)
                    a = fmaf(nde[jj * DDIRIN + q], sW[q * DDIR + lane], a);
                s += silu_f(a);
            }
        }
        outn[128 + lane] = s * invv;
    }

    // sender atom (192..320)
    {
        float s0 = 0.0f, s1 = 0.0f;
#pragma unroll 4
        for (int i = 0; i < cnt; ++i) {
            int a = s_aidx[wid][i];
            s0 += semb[a * DD + lane];
            s1 += semb[a * DD + 64 + lane];
        }
        outn[192 + lane] = s0 * invv;
        outn[256 + lane] = s1 * invv;
    }

    // recv dir (320..384)
    {
        float tdv;
        if constexpr (USE_WS) {
            tdv = td_ws[n * DDIR + lane];
        } else {
            float a = tb[lane];
#pragma unroll
            for (int q = 0; q < DDIRIN; ++q)
                a = fmaf(nde[n * DDIRIN + q], tW[q * DDIR + lane], a);
            tdv = silu_f(a);
        }
        outn[320 + lane] = tdv * scale;
    }

    // recv atom (384..512)
    {
        int ann = an[n];
        outn[384 + lane] = temb[ann * DD + lane] * scale;
        outn[448 + lane] = temb[ann * DD + 64 + lane] * scale;
    }
}

extern "C" void kernel_launch(void* const* d_in, const int* in_sizes, int n_in,
                              void* d_out, int out_size, void* d_ws, size_t ws_size,
                              hipStream_t stream) {
    const int*   an    = (const int*)  d_in[0];
    const float* nde   = (const float*)d_in[1];
    const float* edist = (const float*)d_in[2];
    const int*   nl    = (const int*)  d_in[3];
    const int*   nmask = (const int*)  d_in[4];
    const float* semb  = (const float*)d_in[5];
    const float* temb  = (const float*)d_in[6];
    const float* sW    = (const float*)d_in[7];
    const float* sb    = (const float*)d_in[8];
    const float* tW    = (const float*)d_in[9];
    const float* tb    = (const float*)d_in[10];
    const float* dW    = (const float*)d_in[11];
    const float* db    = (const float*)d_in[12];
    float* out = (float*)d_out;

    const size_t dwb_bytes = (size_t)DD * DD * sizeof(ushort);              // 32 KB
    const size_t need = dwb_bytes + (size_t)NN * DDIR * sizeof(float) * 2;  // +5.12 MB

    if (ws_size >= need) {
        ushort* dWb = (ushort*)d_ws;
        float*  sd  = (float*)((char*)d_ws + dwb_bytes);
        float*  td  = sd + (size_t)NN * DDIR;
        dirprep_kernel<<<32 + NN * DDIR / 256, 256, 0, stream>>>(
            nde, sW, sb, tW, tb, dW, sd, td, dWb);
        gemm_kernel<true><<<NN / 4, 256, 0, stream>>>(edist, nmask, dW, db, dWb, out);
        seg_kernel<true><<<NN / 4, 256, 0, stream>>>(
            an, nde, nl, nmask, semb, temb, sW, sb, tW, tb, sd, td, out);
    } else {
        gemm_kernel<false><<<NN / 4, 256, 0, stream>>>(edist, nmask, dW, db, nullptr, out);
        seg_kernel<false><<<NN / 4, 256, 0, stream>>>(
            an, nde, nl, nmask, semb, temb, sW, sb, tW, tb, nullptr, nullptr, out);
    }
}